// Round 11
// baseline (53.154 us; speedup 1.0000x reference)
//
#include <hip/hip_runtime.h>
#include <hip/hip_bf16.h>

// Problem constants: B=8, T=128, n=127 neighbors, Q=K=64, H=4, O=H*K=256
#define NB 127
#define SCALE 2.885390081777927f   // 2*log2(e): folds tanh's e^{2x} into one exp2

typedef __attribute__((ext_vector_type(8))) short bf16x8;
typedef __attribute__((ext_vector_type(4))) float f32x4;

// ws layout: packed bf16 MFMA fragments, 4 x 32KB (short offsets).
// Wk and Wq are PRE-SCALED by SCALE in the pack kernel.
#define WKP_S  0
#define WVP_S  16384
#define WQP_S  32768
#define WVQP_S 49152
#define WS_NEEDED ((size_t)(4 * 16384 * 2))

__device__ __forceinline__ short bfs(float f) {
  __hip_bfloat16 h = __float2bfloat16(f);
  return __builtin_bit_cast(short, h);
}
__device__ __forceinline__ unsigned packbf2(float a, float b) {
  unsigned lo = (unsigned short)bfs(a);
  unsigned hi = (unsigned short)bfs(b);
  return lo | (hi << 16);
}
__device__ __forceinline__ float b2f(short s) {
  unsigned u = ((unsigned)(unsigned short)s) << 16;
  return __builtin_bit_cast(float, u);
}
__device__ __forceinline__ bf16x8 gath_s(const float* __restrict__ p, float s) {
  float4 a = *(const float4*)p;
  float4 b = *(const float4*)(p + 4);
  bf16x8 f;
  f[0] = bfs(a.x * s); f[1] = bfs(a.y * s); f[2] = bfs(a.z * s); f[3] = bfs(a.w * s);
  f[4] = bfs(b.x * s); f[5] = bfs(b.y * s); f[6] = bfs(b.z * s); f[7] = bfs(b.w * s);
  return f;
}

// ================= pack kernel (grid 64): coalesced f32 reads -> fragment-order bf16 ====
// frag layout: lane (= g*16 + l15) of fragment (head,nt,kt) holds
//   W[o = head*64 + nt*16 + l15][k = g*8 + kt*32 + j], j=0..7
__global__ __launch_bounds__(256, 2) void
pack_kernel(const float* __restrict__ Wk, const float* __restrict__ Wq,
            const float* __restrict__ Wv, short* __restrict__ dstall)
{
  const int blk = blockIdx.x;
  const int tid = threadIdx.x;
  const int m = blk >> 4, sub = blk & 15;
  const float* src; int stride, off, dsto; float scl;
  if (m == 0)      { src = Wk; stride = 64;  off = 0;  dsto = WKP_S;  scl = SCALE; }
  else if (m == 1) { src = Wv; stride = 128; off = 0;  dsto = WVP_S;  scl = 1.f; }  // Wv kv
  else if (m == 2) { src = Wq; stride = 64;  off = 0;  dsto = WQP_S;  scl = SCALE; }
  else             { src = Wv; stride = 128; off = 64; dsto = WVQP_S; scl = 1.f; }  // Wv q
  short* dst = dstall + dsto;
  int i4 = sub * 256 + tid;               // float4 index in 256x64 submatrix
  int o = i4 >> 4, c4 = i4 & 15;
  float4 v = ((const float4*)(src + o * stride + off))[c4];
  int k0 = c4 * 4;
  int kt = k0 >> 5, gg = (k0 & 31) >> 3, j0 = k0 & 7;
  int head = o >> 6, nt = (o >> 4) & 3, ol = o & 15;
  int di = ((((head * 4 + nt) * 2 + kt) * 64) + gg * 16 + ol) * 8 + j0;
  *(uint2*)(dst + di) = make_uint2(packbf2(v.x * scl, v.y * scl),
                                   packbf2(v.z * scl, v.w * scl));
}

// ================= main kernel (grid 512, 2 bt per block, wave = head) =================
// R10 pipeline (proven spill-free at the (256,4) 128-reg cap), run twice per block
// over two upfront-staged kv tiles. scs/qv_lds are wave-private -> reused across
// the two bt with no extra barrier. Tests the block-dispatch-overhead hypothesis.
template <int PREP>
__global__ __launch_bounds__(256, 4) void
rnn_attn_kernel(const float* __restrict__ q_x, const float* __restrict__ kv_x,
                const float* __restrict__ Wk, const float* __restrict__ Wq,
                const float* __restrict__ Wv, const float* __restrict__ bv,
                const float* __restrict__ bias, const float* __restrict__ wsc,
                const short* __restrict__ pack, float* __restrict__ out)
{
  __shared__ __align__(16) unsigned char Atile[2][128 * 128];   // 32 KB
  __shared__ float scs[4][128];        // per-head scores -> softmax weights (reused per bt)
  __shared__ float4 qv_lds[4][4][4];   // [head][nt][g] (reused per bt)

  const int tid = threadIdx.x;
  const int bt0 = blockIdx.x * 2;
  const int lane = tid & 63;
  const int head = tid >> 6;
  const int l15 = lane & 15;
  const int g = lane >> 4;

  // ---- stage BOTH kv tiles (127x64 f32 -> bf16, XOR-swizzled), coalesced ----
  #pragma unroll
  for (int i = 0; i < 16; ++i) {
    int idx = i * 256 + tid;
    int tb = idx >> 11;                 // which tile
    int id2 = idx & 2047;
    int row = id2 >> 4, c = id2 & 15;
    const float* kv = kv_x + (size_t)(bt0 + tb) * (NB * 64);
    float4 v = (row < NB) ? ((const float4*)kv)[id2] : make_float4(0.f, 0.f, 0.f, 0.f);
    int byte = (tb << 14) + ((((row << 7) + (c << 3))) ^ ((row & 7) << 4));
    *(uint2*)(&Atile[0][0] + byte) = make_uint2(packbf2(v.x, v.y), packbf2(v.z, v.w));
  }
  __syncthreads();

  #pragma unroll 1
  for (int b = 0; b < 2; ++b) {
    const int bt = bt0 + b;
    const int tbase = b << 14;

    // ---- prologue: qq/qv via broadcast-B MFMA ----
    f32x4 qq[4];
    {
      bf16x8 qf0 = gath_s(q_x + bt * 64 + g * 8, 1.f);
      bf16x8 qf1 = gath_s(q_x + bt * 64 + 32 + g * 8, 1.f);
      #pragma unroll
      for (int nt = 0; nt < 4; ++nt) {
        bf16x8 wv0, wv1;
        if (PREP) {
          const bf16x8* pv = (const bf16x8*)(pack + WVQP_S);
          wv0 = pv[((head * 4 + nt) * 2 + 0) * 64 + lane];
          wv1 = pv[((head * 4 + nt) * 2 + 1) * 64 + lane];
        } else {
          int o = head * 64 + nt * 16 + l15;
          wv0 = gath_s(Wv + o * 128 + 64 + g * 8, 1.f);
          wv1 = gath_s(Wv + o * 128 + 64 + 32 + g * 8, 1.f);
        }
        float4 bv4 = ((const float4*)(bv + head * 64))[nt * 4 + g];
        f32x4 bb = (f32x4){bv4.x, bv4.y, bv4.z, bv4.w};
        bb = __builtin_amdgcn_mfma_f32_16x16x32_bf16(wv0, qf0, bb, 0, 0, 0);
        bb = __builtin_amdgcn_mfma_f32_16x16x32_bf16(wv1, qf1, bb, 0, 0, 0);
        if (l15 == 0) qv_lds[head][nt][g] = make_float4(bb[0], bb[1], bb[2], bb[3]);
      }
      #pragma unroll
      for (int nt = 0; nt < 4; ++nt) {
        bf16x8 wq0, wq1;
        if (PREP) {
          const bf16x8* pw = (const bf16x8*)(pack + WQP_S);
          wq0 = pw[((head * 4 + nt) * 2 + 0) * 64 + lane];
          wq1 = pw[((head * 4 + nt) * 2 + 1) * 64 + lane];
        } else {
          int o = head * 64 + nt * 16 + l15;
          wq0 = gath_s(Wq + o * 64 + g * 8, SCALE);
          wq1 = gath_s(Wq + o * 64 + 32 + g * 8, SCALE);
        }
        float4 bs4 = ((const float4*)bias)[nt * 4 + g];
        f32x4 a = (f32x4){bs4.x * SCALE, bs4.y * SCALE, bs4.z * SCALE, bs4.w * SCALE};
        a = __builtin_amdgcn_mfma_f32_16x16x32_bf16(wq0, qf0, a, 0, 0, 0);
        a = __builtin_amdgcn_mfma_f32_16x16x32_bf16(wq1, qf1, a, 0, 0, 0);
        qq[nt] = a;
      }
    }

    // ---- Phase C: keys^T GEMM + score, two o-halves ----
    #pragma unroll
    for (int h = 0; h < 2; ++h) {
      bf16x8 b00, b01, b10, b11;
      if (PREP) {
        const bf16x8* pw = (const bf16x8*)(pack + WKP_S);
        b00 = pw[((head * 4 + 2 * h + 0) * 2 + 0) * 64 + lane];
        b01 = pw[((head * 4 + 2 * h + 0) * 2 + 1) * 64 + lane];
        b10 = pw[((head * 4 + 2 * h + 1) * 2 + 0) * 64 + lane];
        b11 = pw[((head * 4 + 2 * h + 1) * 2 + 1) * 64 + lane];
      } else {
        int o0 = head * 64 + (2 * h) * 16 + l15;
        b00 = gath_s(Wk + o0 * 64 + g * 8, SCALE);
        b01 = gath_s(Wk + o0 * 64 + 32 + g * 8, SCALE);
        b10 = gath_s(Wk + (o0 + 16) * 64 + g * 8, SCALE);
        b11 = gath_s(Wk + (o0 + 16) * 64 + 32 + g * 8, SCALE);
      }
      float4 ta = ((const float4*)wsc)[(2 * h) * 4 + g];
      float4 tb = ((const float4*)wsc)[(2 * h + 1) * 4 + g];
      f32x4 wsa = (f32x4){-2.f * ta.x, -2.f * ta.y, -2.f * ta.z, -2.f * ta.w};
      f32x4 wsb = (f32x4){-2.f * tb.x, -2.f * tb.y, -2.f * tb.z, -2.f * tb.w};
      f32x4 qa = qq[2 * h], qb = qq[2 * h + 1];

      #pragma unroll 1
      for (int mt = 0; mt < 8; ++mt) {
        int row = mt * 16 + l15;
        int byte0 = tbase + (row << 7) + g * 16;
        int swz = (l15 & 7) << 4;
        bf16x8 a0 = *(const bf16x8*)(&Atile[0][0] + (byte0 ^ swz));
        bf16x8 a1 = *(const bf16x8*)(&Atile[0][0] + ((byte0 + 64) ^ swz));
        float p = 0.f;
        f32x4 acc = qa;
        acc = __builtin_amdgcn_mfma_f32_16x16x32_bf16(b00, a0, acc, 0, 0, 0);
        acc = __builtin_amdgcn_mfma_f32_16x16x32_bf16(b01, a1, acc, 0, 0, 0);
        #pragma unroll
        for (int r = 0; r < 4; ++r)
          p = fmaf(wsa[r], __builtin_amdgcn_rcpf(__builtin_amdgcn_exp2f(acc[r]) + 1.f), p);
        f32x4 acc2 = qb;
        acc2 = __builtin_amdgcn_mfma_f32_16x16x32_bf16(b10, a0, acc2, 0, 0, 0);
        acc2 = __builtin_amdgcn_mfma_f32_16x16x32_bf16(b11, a1, acc2, 0, 0, 0);
        #pragma unroll
        for (int r = 0; r < 4; ++r)
          p = fmaf(wsb[r], __builtin_amdgcn_rcpf(__builtin_amdgcn_exp2f(acc2[r]) + 1.f), p);
        p += __shfl_xor(p, 16);    // sum over o across g-groups
        p += __shfl_xor(p, 32);
        if (g == 0) {
          int idx = mt * 16 + l15;
          scs[head][idx] = h ? (scs[head][idx] + p) : p;
        }
      }
    }

    // ---- Phase D: softmax over n=127 (wave-private, static offsets) ----
    {
      float s0 = scs[head][l15 + 0],  s1 = scs[head][l15 + 16];
      float s2 = scs[head][l15 + 32], s3 = scs[head][l15 + 48];
      float s4 = scs[head][l15 + 64], s5 = scs[head][l15 + 80];
      float s6 = scs[head][l15 + 96], s7 = scs[head][l15 + 112];
      if (l15 == 15) s7 = -3.0e38f;   // mask pad row n=127
      float m = fmaxf(fmaxf(fmaxf(s0, s1), fmaxf(s2, s3)),
                      fmaxf(fmaxf(s4, s5), fmaxf(s6, s7)));
      #pragma unroll
      for (int d = 1; d < 16; d <<= 1) m = fmaxf(m, __shfl_xor(m, d));
      float e0 = __expf(s0 - m), e1 = __expf(s1 - m), e2 = __expf(s2 - m), e3 = __expf(s3 - m);
      float e4 = __expf(s4 - m), e5 = __expf(s5 - m), e6 = __expf(s6 - m), e7 = __expf(s7 - m);
      float sum = ((e0 + e1) + (e2 + e3)) + ((e4 + e5) + (e6 + e7));
      #pragma unroll
      for (int d = 1; d < 16; d <<= 1) sum += __shfl_xor(sum, d);
      float inv = __builtin_amdgcn_rcpf(sum);
      if (g == 0) {
        scs[head][l15 + 0]  = e0 * inv; scs[head][l15 + 16] = e1 * inv;
        scs[head][l15 + 32] = e2 * inv; scs[head][l15 + 48] = e3 * inv;
        scs[head][l15 + 64] = e4 * inv; scs[head][l15 + 80] = e5 * inv;
        scs[head][l15 + 96] = e6 * inv; scs[head][l15 + 112] = e7 * inv;
      }
    }

    // ---- Phase E: pvp[k] = sum_n P[n]*kv[n,k], single VALU tile sweep ----
    float pvp0[8], pvp1[8];
    #pragma unroll
    for (int j = 0; j < 8; ++j) { pvp0[j] = 0.f; pvp1[j] = 0.f; }
    #pragma unroll 1
    for (int mt = 0; mt < 8; ++mt) {
      int row = mt * 16 + l15;
      int byte0 = tbase + (row << 7) + g * 16;
      int swz = (l15 & 7) << 4;
      bf16x8 a0 = *(const bf16x8*)(&Atile[0][0] + (byte0 ^ swz));
      bf16x8 a1 = *(const bf16x8*)(&Atile[0][0] + ((byte0 + 64) ^ swz));
      float w = scs[head][mt * 16 + l15];   // broadcast across g-groups
      #pragma unroll
      for (int j = 0; j < 8; ++j) {
        pvp0[j] = fmaf(w, b2f(a0[j]), pvp0[j]);
        pvp1[j] = fmaf(w, b2f(a1[j]), pvp1[j]);
      }
    }
    bf16x8 pa0, pa1;
    #pragma unroll
    for (int j = 0; j < 8; ++j) { pa0[j] = bfs(pvp0[j]); pa1[j] = bfs(pvp1[j]); }

    // ---- GEMV: out[o] = sum_k pv[k]*Wv_kv[o,k]; MFMA i-dim folds the 16 partials ----
    float tt[4];
    #pragma unroll 2
    for (int nt = 0; nt < 4; ++nt) {
      bf16x8 bw0, bw1;
      if (PREP) {
        const bf16x8* pw = (const bf16x8*)(pack + WVP_S);
        bw0 = pw[((head * 4 + nt) * 2 + 0) * 64 + lane];
        bw1 = pw[((head * 4 + nt) * 2 + 1) * 64 + lane];
      } else {
        int o = head * 64 + nt * 16 + l15;
        bw0 = gath_s(Wv + o * 128 + g * 8, 1.f);
        bw1 = gath_s(Wv + o * 128 + 32 + g * 8, 1.f);
      }
      f32x4 c = (f32x4){0.f, 0.f, 0.f, 0.f};
      c = __builtin_amdgcn_mfma_f32_16x16x32_bf16(pa0, bw0, c, 0, 0, 0);
      c = __builtin_amdgcn_mfma_f32_16x16x32_bf16(pa1, bw1, c, 0, 0, 0);
      float t = (c[0] + c[1]) + (c[2] + c[3]);
      t += __shfl_xor(t, 16);
      t += __shfl_xor(t, 32);
      tt[nt] = t;            // out-partial for o = nt*16 + l15, valid in all lanes
    }

    // ---- store: lane (l15,g) writes o = g*16 + l15 -> fully coalesced ----
    float v = tt[0];
    v = (g == 1) ? tt[1] : v;
    v = (g == 2) ? tt[2] : v;
    v = (g == 3) ? tt[3] : v;
    float qv = ((const float*)&qv_lds[head][g][l15 >> 2])[l15 & 3];
    out[bt * 256 + head * 64 + lane] = v + qv;
  }
}

extern "C" void kernel_launch(void* const* d_in, const int* in_sizes, int n_in,
                              void* d_out, int out_size, void* d_ws, size_t ws_size,
                              hipStream_t stream) {
  const float* q_x  = (const float*)d_in[0];
  const float* kv_x = (const float*)d_in[1];
  const float* Wk   = (const float*)d_in[2];
  const float* Wq   = (const float*)d_in[3];
  const float* Wv   = (const float*)d_in[4];
  const float* bv   = (const float*)d_in[5];
  const float* bias = (const float*)d_in[6];
  const float* wsc  = (const float*)d_in[7];
  // d_in[8] = bs: constant across neighbors -> cancels in softmax, unused.
  float* out = (float*)d_out;
  short* pack = (short*)d_ws;

  if (ws_size >= WS_NEEDED) {
    pack_kernel<<<64, 256, 0, stream>>>(Wk, Wq, Wv, pack);
    rnn_attn_kernel<1><<<512, 256, 0, stream>>>(q_x, kv_x, Wk, Wq, Wv, bv, bias, wsc, pack, out);
  } else {
    rnn_attn_kernel<0><<<512, 256, 0, stream>>>(q_x, kv_x, Wk, Wq, Wv, bv, bias, wsc, pack, out);
  }
}

// Round 13
// 42.837 us; speedup vs baseline: 1.2408x; 1.2408x over previous
//
#include <hip/hip_runtime.h>
#include <hip/hip_bf16.h>

// Problem constants: B=8, T=128, n=127 neighbors, Q=K=64, H=4, O=H*K=256
#define NB 127
#define SCALE 2.885390081777927f   // 2*log2(e): folds tanh's e^{2x} into one exp2

typedef __attribute__((ext_vector_type(8))) short bf16x8;
typedef __attribute__((ext_vector_type(4))) float f32x4;

__device__ __forceinline__ short bfs(float f) {
  __hip_bfloat16 h = __float2bfloat16(f);
  return __builtin_bit_cast(short, h);
}
__device__ __forceinline__ unsigned packbf2(float a, float b) {
  unsigned lo = (unsigned short)bfs(a);
  unsigned hi = (unsigned short)bfs(b);
  return lo | (hi << 16);
}
__device__ __forceinline__ float b2f(short s) {
  unsigned u = ((unsigned)(unsigned short)s) << 16;
  return __builtin_bit_cast(float, u);
}
// gather 8 consecutive floats -> bf16 fragment, scaled
__device__ __forceinline__ bf16x8 gath_s(const float* __restrict__ p, float s) {
  float4 a = *(const float4*)p;
  float4 b = *(const float4*)(p + 4);
  bf16x8 f;
  f[0] = bfs(a.x * s); f[1] = bfs(a.y * s); f[2] = bfs(a.z * s); f[3] = bfs(a.w * s);
  f[4] = bfs(b.x * s); f[5] = bfs(b.y * s); f[6] = bfs(b.z * s); f[7] = bfs(b.w * s);
  return f;
}

// ================= main kernel (grid 1024, wave = head), SINGLE LAUNCH =================
// R10 structure (proven 29.1us, spill-free at the (256,4) 128-reg cap), direct
// global weight loads (weights are 112KB -> L2-resident after warmup), no pack
// kernel, no software pipelining (R12 proved it miscompiles around the LDS RMW).
// Unroll discipline: h-loop and GEMV at unroll 1 (gath_s transients bounded),
// prologue at unroll 2 (R8-proven shape).
__global__ __launch_bounds__(256, 4) void
rnn_attn_kernel(const float* __restrict__ q_x, const float* __restrict__ kv_x,
                const float* __restrict__ Wk, const float* __restrict__ Wq,
                const float* __restrict__ Wv, const float* __restrict__ bv,
                const float* __restrict__ bias, const float* __restrict__ wsc,
                float* __restrict__ out)
{
  __shared__ __align__(16) unsigned char Atile[128 * 128];
  __shared__ float scs[4][128];        // per-head scores -> softmax weights
  __shared__ float4 qv_lds[4][4][4];   // [head][nt][g] : qv[o = nt*16+g*4+r]

  const int tid = threadIdx.x;
  const int bt = blockIdx.x;
  const int lane = tid & 63;
  const int head = tid >> 6;
  const int l15 = lane & 15;
  const int g = lane >> 4;

  // ---- stage kv tile (127x64 f32 -> bf16, XOR-swizzled), coalesced ----
  const float* kv = kv_x + (size_t)bt * (NB * 64);
  #pragma unroll
  for (int i = 0; i < 8; ++i) {
    int idx = i * 256 + tid;
    int row = idx >> 4, c = idx & 15;
    float4 v = (row < NB) ? ((const float4*)kv)[idx] : make_float4(0.f, 0.f, 0.f, 0.f);
    int byte = (row << 7) + (c << 3);
    byte ^= ((row & 7) << 4);
    *(uint2*)(&Atile[byte]) = make_uint2(packbf2(v.x, v.y), packbf2(v.z, v.w));
  }

  // ---- prologue: qq/qv via broadcast-B MFMA ----
  // qq[nt][r] = SCALE*(q@Wq.T[o] + bias[o&63]), o = head*64+nt*16+g*4+r
  f32x4 qq[4];
  {
    bf16x8 qf0 = gath_s(q_x + bt * 64 + g * 8, 1.f);
    bf16x8 qf1 = gath_s(q_x + bt * 64 + 32 + g * 8, 1.f);
    // qv first: wv-frags die before wq-frags load
    #pragma unroll 2
    for (int nt = 0; nt < 4; ++nt) {
      int o = head * 64 + nt * 16 + l15;
      bf16x8 wv0 = gath_s(Wv + o * 128 + 64 + g * 8, 1.f);
      bf16x8 wv1 = gath_s(Wv + o * 128 + 64 + 32 + g * 8, 1.f);
      float4 bv4 = ((const float4*)(bv + head * 64))[nt * 4 + g];
      f32x4 b = (f32x4){bv4.x, bv4.y, bv4.z, bv4.w};
      b = __builtin_amdgcn_mfma_f32_16x16x32_bf16(wv0, qf0, b, 0, 0, 0);
      b = __builtin_amdgcn_mfma_f32_16x16x32_bf16(wv1, qf1, b, 0, 0, 0);
      if (l15 == 0) qv_lds[head][nt][g] = make_float4(b[0], b[1], b[2], b[3]);
    }
    #pragma unroll 2
    for (int nt = 0; nt < 4; ++nt) {
      int o = head * 64 + nt * 16 + l15;
      bf16x8 wq0 = gath_s(Wq + o * 64 + g * 8, SCALE);
      bf16x8 wq1 = gath_s(Wq + o * 64 + 32 + g * 8, SCALE);
      float4 bs4 = ((const float4*)bias)[nt * 4 + g];
      f32x4 a = (f32x4){bs4.x * SCALE, bs4.y * SCALE, bs4.z * SCALE, bs4.w * SCALE};
      a = __builtin_amdgcn_mfma_f32_16x16x32_bf16(wq0, qf0, a, 0, 0, 0);
      a = __builtin_amdgcn_mfma_f32_16x16x32_bf16(wq1, qf1, a, 0, 0, 0);
      qq[nt] = a;
    }
  }

  __syncthreads();

  // ---- Phase C: keys^T GEMM + score, two o-halves ----
  // score'_n = sum_o (-2 ws_o) / (exp2(acc)+1), acc = SCALE*(keys+queries+bias)
  #pragma unroll 1
  for (int h = 0; h < 2; ++h) {
    int o0 = head * 64 + (2 * h) * 16 + l15;
    bf16x8 b00 = gath_s(Wk + o0 * 64 + g * 8, SCALE);
    bf16x8 b01 = gath_s(Wk + o0 * 64 + 32 + g * 8, SCALE);
    bf16x8 b10 = gath_s(Wk + (o0 + 16) * 64 + g * 8, SCALE);
    bf16x8 b11 = gath_s(Wk + (o0 + 16) * 64 + 32 + g * 8, SCALE);
    float4 ta = ((const float4*)wsc)[(2 * h) * 4 + g];
    float4 tb = ((const float4*)wsc)[(2 * h + 1) * 4 + g];
    f32x4 wsa = (f32x4){-2.f * ta.x, -2.f * ta.y, -2.f * ta.z, -2.f * ta.w};
    f32x4 wsb = (f32x4){-2.f * tb.x, -2.f * tb.y, -2.f * tb.z, -2.f * tb.w};
    f32x4 qa = qq[2 * h], qb = qq[2 * h + 1];

    #pragma unroll 1
    for (int mt = 0; mt < 8; ++mt) {
      int row = mt * 16 + l15;
      int byte0 = (row << 7) + g * 16;
      int swz = (l15 & 7) << 4;
      bf16x8 a0 = *(const bf16x8*)(&Atile[byte0 ^ swz]);
      bf16x8 a1 = *(const bf16x8*)(&Atile[(byte0 + 64) ^ swz]);
      float p = 0.f;
      f32x4 acc = qa;
      acc = __builtin_amdgcn_mfma_f32_16x16x32_bf16(b00, a0, acc, 0, 0, 0);
      acc = __builtin_amdgcn_mfma_f32_16x16x32_bf16(b01, a1, acc, 0, 0, 0);
      #pragma unroll
      for (int r = 0; r < 4; ++r)
        p = fmaf(wsa[r], __builtin_amdgcn_rcpf(__builtin_amdgcn_exp2f(acc[r]) + 1.f), p);
      f32x4 acc2 = qb;
      acc2 = __builtin_amdgcn_mfma_f32_16x16x32_bf16(b10, a0, acc2, 0, 0, 0);
      acc2 = __builtin_amdgcn_mfma_f32_16x16x32_bf16(b11, a1, acc2, 0, 0, 0);
      #pragma unroll
      for (int r = 0; r < 4; ++r)
        p = fmaf(wsb[r], __builtin_amdgcn_rcpf(__builtin_amdgcn_exp2f(acc2[r]) + 1.f), p);
      p += __shfl_xor(p, 16);    // sum over o across g-groups
      p += __shfl_xor(p, 32);
      if (g == 0) {
        int idx = mt * 16 + l15;
        scs[head][idx] = h ? (scs[head][idx] + p) : p;
      }
    }
  }

  // ---- Phase D: softmax over n=127 (wave-private, static offsets) ----
  {
    float s0 = scs[head][l15 + 0],  s1 = scs[head][l15 + 16];
    float s2 = scs[head][l15 + 32], s3 = scs[head][l15 + 48];
    float s4 = scs[head][l15 + 64], s5 = scs[head][l15 + 80];
    float s6 = scs[head][l15 + 96], s7 = scs[head][l15 + 112];
    if (l15 == 15) s7 = -3.0e38f;   // mask pad row n=127
    float m = fmaxf(fmaxf(fmaxf(s0, s1), fmaxf(s2, s3)),
                    fmaxf(fmaxf(s4, s5), fmaxf(s6, s7)));
    #pragma unroll
    for (int d = 1; d < 16; d <<= 1) m = fmaxf(m, __shfl_xor(m, d));
    float e0 = __expf(s0 - m), e1 = __expf(s1 - m), e2 = __expf(s2 - m), e3 = __expf(s3 - m);
    float e4 = __expf(s4 - m), e5 = __expf(s5 - m), e6 = __expf(s6 - m), e7 = __expf(s7 - m);
    float sum = ((e0 + e1) + (e2 + e3)) + ((e4 + e5) + (e6 + e7));
    #pragma unroll
    for (int d = 1; d < 16; d <<= 1) sum += __shfl_xor(sum, d);
    float inv = __builtin_amdgcn_rcpf(sum);
    if (g == 0) {
      scs[head][l15 + 0]  = e0 * inv; scs[head][l15 + 16] = e1 * inv;
      scs[head][l15 + 32] = e2 * inv; scs[head][l15 + 48] = e3 * inv;
      scs[head][l15 + 64] = e4 * inv; scs[head][l15 + 80] = e5 * inv;
      scs[head][l15 + 96] = e6 * inv; scs[head][l15 + 112] = e7 * inv;
    }
  }

  // ---- Phase E: pvp[k] = sum_n P[n]*kv[n,k], single VALU tile sweep ----
  float pvp0[8], pvp1[8];
  #pragma unroll
  for (int j = 0; j < 8; ++j) { pvp0[j] = 0.f; pvp1[j] = 0.f; }
  #pragma unroll 1
  for (int mt = 0; mt < 8; ++mt) {
    int row = mt * 16 + l15;
    int byte0 = (row << 7) + g * 16;
    int swz = (l15 & 7) << 4;
    bf16x8 a0 = *(const bf16x8*)(&Atile[byte0 ^ swz]);
    bf16x8 a1 = *(const bf16x8*)(&Atile[(byte0 + 64) ^ swz]);
    float w = scs[head][mt * 16 + l15];   // broadcast across g-groups
    #pragma unroll
    for (int j = 0; j < 8; ++j) {
      pvp0[j] = fmaf(w, b2f(a0[j]), pvp0[j]);
      pvp1[j] = fmaf(w, b2f(a1[j]), pvp1[j]);
    }
  }
  // pvp is an A-fragment: lane (l15,g) = pv_partial[group=l15][k = g*8+j (+32)]
  bf16x8 pa0, pa1;
  #pragma unroll
  for (int j = 0; j < 8; ++j) { pa0[j] = bfs(pvp0[j]); pa1[j] = bfs(pvp1[j]); }

  // ---- GEMV: out[o] = sum_k pv[k]*Wv_kv[o,k]; MFMA i-dim folds the 16 partials ----
  float tt[4];
  #pragma unroll 1
  for (int nt = 0; nt < 4; ++nt) {
    int o = head * 64 + nt * 16 + l15;
    bf16x8 bw0 = gath_s(Wv + o * 128 + g * 8, 1.f);
    bf16x8 bw1 = gath_s(Wv + o * 128 + 32 + g * 8, 1.f);
    f32x4 c = (f32x4){0.f, 0.f, 0.f, 0.f};
    c = __builtin_amdgcn_mfma_f32_16x16x32_bf16(pa0, bw0, c, 0, 0, 0);
    c = __builtin_amdgcn_mfma_f32_16x16x32_bf16(pa1, bw1, c, 0, 0, 0);
    float t = (c[0] + c[1]) + (c[2] + c[3]);
    t += __shfl_xor(t, 16);
    t += __shfl_xor(t, 32);
    tt[nt] = t;            // out-partial for o = nt*16 + l15, valid in all lanes
  }

  // ---- store: lane (l15,g) writes o = g*16 + l15 -> fully coalesced ----
  float v = tt[0];
  v = (g == 1) ? tt[1] : v;
  v = (g == 2) ? tt[2] : v;
  v = (g == 3) ? tt[3] : v;
  float qv = ((const float*)&qv_lds[head][g][l15 >> 2])[l15 & 3];
  out[bt * 256 + head * 64 + lane] = v + qv;
}

extern "C" void kernel_launch(void* const* d_in, const int* in_sizes, int n_in,
                              void* d_out, int out_size, void* d_ws, size_t ws_size,
                              hipStream_t stream) {
  const float* q_x  = (const float*)d_in[0];
  const float* kv_x = (const float*)d_in[1];
  const float* Wk   = (const float*)d_in[2];
  const float* Wq   = (const float*)d_in[3];
  const float* Wv   = (const float*)d_in[4];
  const float* bv   = (const float*)d_in[5];
  const float* bias = (const float*)d_in[6];
  const float* wsc  = (const float*)d_in[7];
  // d_in[8] = bs: constant across neighbors -> cancels in softmax, unused.
  float* out = (float*)d_out;

  rnn_attn_kernel<<<1024, 256, 0, stream>>>(q_x, kv_x, Wk, Wq, Wv, bv, bias, wsc, out);
}

// Round 14
// 34.306 us; speedup vs baseline: 1.5494x; 1.2487x over previous
//
#include <hip/hip_runtime.h>
#include <hip/hip_bf16.h>

// Problem constants: B=8, T=128, n=127 neighbors, Q=K=64, H=4, O=H*K=256
#define NB 127
#define SCALE 2.885390081777927f   // 2*log2(e): folds tanh's e^{2x} into one exp2

typedef __attribute__((ext_vector_type(8))) short bf16x8;
typedef __attribute__((ext_vector_type(4))) float f32x4;

// ws layout: packed bf16 MFMA fragments, 4 x 32KB (short offsets).
// Wk and Wq are PRE-SCALED by SCALE in the pack kernel.
#define WKP_S  0
#define WVP_S  16384
#define WQP_S  32768
#define WVQP_S 49152
#define WS_NEEDED ((size_t)(4 * 16384 * 2))

__device__ __forceinline__ short bfs(float f) {
  __hip_bfloat16 h = __float2bfloat16(f);
  return __builtin_bit_cast(short, h);
}
__device__ __forceinline__ unsigned packbf2(float a, float b) {
  unsigned lo = (unsigned short)bfs(a);
  unsigned hi = (unsigned short)bfs(b);
  return lo | (hi << 16);
}
__device__ __forceinline__ float b2f(short s) {
  unsigned u = ((unsigned)(unsigned short)s) << 16;
  return __builtin_bit_cast(float, u);
}
__device__ __forceinline__ bf16x8 gath_s(const float* __restrict__ p, float s) {
  float4 a = *(const float4*)p;
  float4 b = *(const float4*)(p + 4);
  bf16x8 f;
  f[0] = bfs(a.x * s); f[1] = bfs(a.y * s); f[2] = bfs(a.z * s); f[3] = bfs(a.w * s);
  f[4] = bfs(b.x * s); f[5] = bfs(b.y * s); f[6] = bfs(b.z * s); f[7] = bfs(b.w * s);
  return f;
}

// ================= pack kernel (grid 64): coalesced f32 reads -> fragment-order bf16 ====
// frag layout: lane (= g*16 + l15) of fragment (head,nt,kt) holds
//   W[o = head*64 + nt*16 + l15][k = g*8 + kt*32 + j], j=0..7
__global__ __launch_bounds__(256, 2) void
pack_kernel(const float* __restrict__ Wk, const float* __restrict__ Wq,
            const float* __restrict__ Wv, short* __restrict__ dstall)
{
  const int blk = blockIdx.x;
  const int tid = threadIdx.x;
  const int m = blk >> 4, sub = blk & 15;
  const float* src; int stride, off, dsto; float scl;
  if (m == 0)      { src = Wk; stride = 64;  off = 0;  dsto = WKP_S;  scl = SCALE; }
  else if (m == 1) { src = Wv; stride = 128; off = 0;  dsto = WVP_S;  scl = 1.f; }  // Wv kv
  else if (m == 2) { src = Wq; stride = 64;  off = 0;  dsto = WQP_S;  scl = SCALE; }
  else             { src = Wv; stride = 128; off = 64; dsto = WVQP_S; scl = 1.f; }  // Wv q
  short* dst = dstall + dsto;
  int i4 = sub * 256 + tid;               // float4 index in 256x64 submatrix
  int o = i4 >> 4, c4 = i4 & 15;
  float4 v = ((const float4*)(src + o * stride + off))[c4];
  int k0 = c4 * 4;
  int kt = k0 >> 5, gg = (k0 & 31) >> 3, j0 = k0 & 7;
  int head = o >> 6, nt = (o >> 4) & 3, ol = o & 15;
  int di = ((((head * 4 + nt) * 2 + kt) * 64) + gg * 16 + ol) * 8 + j0;
  *(uint2*)(dst + di) = make_uint2(packbf2(v.x * scl, v.y * scl),
                                   packbf2(v.z * scl, v.w * scl));
}

// ================= main kernel (grid 2048, 2 blocks/bt, wave = head-half) =================
// bt = blk & 1023, head-pair hp = blk >> 10 (blocks bt and bt+1024 -> same XCD).
// Wave wv: head_l = wv>>1, half = wv&1; each wave owns rows n in [half*64, half*64+64).
// Halves the per-wave serial chain vs R10 and raises waves/CU; softmax exchanged
// through scs with one extra barrier; PV partials summed via ps.
template <int PREP>
__global__ __launch_bounds__(256, 6) void
rnn_attn_kernel(const float* __restrict__ q_x, const float* __restrict__ kv_x,
                const float* __restrict__ Wk, const float* __restrict__ Wq,
                const float* __restrict__ Wv, const float* __restrict__ bv,
                const float* __restrict__ bias, const float* __restrict__ wsc,
                const short* __restrict__ pack, float* __restrict__ out)
{
  __shared__ __align__(16) unsigned char Atile[128 * 128];
  __shared__ float scs[2][128];       // per local-head scores (written by both halves)
  __shared__ float ps[4][64];         // per-wave PV partials
  __shared__ float4 qv_lds[2][4][4];  // [head_l][nt][g] : qv[o = nt*16+g*4+r]

  const int tid = threadIdx.x;
  const int blk = blockIdx.x;
  const int bt = blk & 1023;
  const int hp = blk >> 10;
  const int lane = tid & 63;
  const int wv = tid >> 6;
  const int head_l = wv >> 1;
  const int half = wv & 1;
  const int head = hp * 2 + head_l;
  const int l15 = lane & 15;
  const int g = lane >> 4;

  // ---- stage kv tile (127x64 f32 -> bf16, XOR-swizzled), coalesced (R10 form) ----
  const float* kv = kv_x + (size_t)bt * (NB * 64);
  #pragma unroll
  for (int i = 0; i < 8; ++i) {
    int idx = i * 256 + tid;
    int row = idx >> 4, c = idx & 15;
    float4 v = (row < NB) ? ((const float4*)kv)[idx] : make_float4(0.f, 0.f, 0.f, 0.f);
    int byte = (row << 7) + (c << 3);
    byte ^= ((row & 7) << 4);
    *(uint2*)(&Atile[byte]) = make_uint2(packbf2(v.x, v.y), packbf2(v.z, v.w));
  }

  // ---- prologue: qq (both halves); qv (half==0 only) via broadcast-B MFMA ----
  f32x4 qq[4];
  {
    bf16x8 qf0 = gath_s(q_x + bt * 64 + g * 8, 1.f);
    bf16x8 qf1 = gath_s(q_x + bt * 64 + 32 + g * 8, 1.f);
    if (half == 0) {
      #pragma unroll 2
      for (int nt = 0; nt < 4; ++nt) {
        bf16x8 wv0, wv1;
        if (PREP) {
          const bf16x8* pv = (const bf16x8*)(pack + WVQP_S);
          wv0 = pv[((head * 4 + nt) * 2 + 0) * 64 + lane];
          wv1 = pv[((head * 4 + nt) * 2 + 1) * 64 + lane];
        } else {
          int o = head * 64 + nt * 16 + l15;
          wv0 = gath_s(Wv + o * 128 + 64 + g * 8, 1.f);
          wv1 = gath_s(Wv + o * 128 + 64 + 32 + g * 8, 1.f);
        }
        float4 bv4 = ((const float4*)(bv + head * 64))[nt * 4 + g];
        f32x4 b = (f32x4){bv4.x, bv4.y, bv4.z, bv4.w};
        b = __builtin_amdgcn_mfma_f32_16x16x32_bf16(wv0, qf0, b, 0, 0, 0);
        b = __builtin_amdgcn_mfma_f32_16x16x32_bf16(wv1, qf1, b, 0, 0, 0);
        if (l15 == 0) qv_lds[head_l][nt][g] = make_float4(b[0], b[1], b[2], b[3]);
      }
    }
    #pragma unroll 2
    for (int nt = 0; nt < 4; ++nt) {
      bf16x8 wq0, wq1;
      if (PREP) {
        const bf16x8* pw = (const bf16x8*)(pack + WQP_S);
        wq0 = pw[((head * 4 + nt) * 2 + 0) * 64 + lane];
        wq1 = pw[((head * 4 + nt) * 2 + 1) * 64 + lane];
      } else {
        int o = head * 64 + nt * 16 + l15;
        wq0 = gath_s(Wq + o * 64 + g * 8, SCALE);
        wq1 = gath_s(Wq + o * 64 + 32 + g * 8, SCALE);
      }
      float4 bs4 = ((const float4*)bias)[nt * 4 + g];
      f32x4 a = (f32x4){bs4.x * SCALE, bs4.y * SCALE, bs4.z * SCALE, bs4.w * SCALE};
      a = __builtin_amdgcn_mfma_f32_16x16x32_bf16(wq0, qf0, a, 0, 0, 0);
      a = __builtin_amdgcn_mfma_f32_16x16x32_bf16(wq1, qf1, a, 0, 0, 0);
      qq[nt] = a;
    }
  }

  __syncthreads();   // barrier 1: Atile staged

  // ---- Phase C: keys^T GEMM + score for this wave's 64 rows, two o-halves ----
  #pragma unroll 1
  for (int h = 0; h < 2; ++h) {
    bf16x8 b00, b01, b10, b11;
    if (PREP) {
      const bf16x8* pw = (const bf16x8*)(pack + WKP_S);
      b00 = pw[((head * 4 + 2 * h + 0) * 2 + 0) * 64 + lane];
      b01 = pw[((head * 4 + 2 * h + 0) * 2 + 1) * 64 + lane];
      b10 = pw[((head * 4 + 2 * h + 1) * 2 + 0) * 64 + lane];
      b11 = pw[((head * 4 + 2 * h + 1) * 2 + 1) * 64 + lane];
    } else {
      int o0 = head * 64 + (2 * h) * 16 + l15;
      b00 = gath_s(Wk + o0 * 64 + g * 8, SCALE);
      b01 = gath_s(Wk + o0 * 64 + 32 + g * 8, SCALE);
      b10 = gath_s(Wk + (o0 + 16) * 64 + g * 8, SCALE);
      b11 = gath_s(Wk + (o0 + 16) * 64 + 32 + g * 8, SCALE);
    }
    float4 ta = ((const float4*)wsc)[(2 * h) * 4 + g];
    float4 tb = ((const float4*)wsc)[(2 * h + 1) * 4 + g];
    f32x4 wsa = (f32x4){-2.f * ta.x, -2.f * ta.y, -2.f * ta.z, -2.f * ta.w};
    f32x4 wsb = (f32x4){-2.f * tb.x, -2.f * tb.y, -2.f * tb.z, -2.f * tb.w};
    f32x4 qa = qq[2 * h], qb = qq[2 * h + 1];

    #pragma unroll 1
    for (int mt = 0; mt < 4; ++mt) {
      int row = half * 64 + mt * 16 + l15;
      int byte0 = (row << 7) + g * 16;
      int swz = (l15 & 7) << 4;
      bf16x8 a0 = *(const bf16x8*)(&Atile[byte0 ^ swz]);
      bf16x8 a1 = *(const bf16x8*)(&Atile[(byte0 + 64) ^ swz]);
      float p = 0.f;
      f32x4 acc = qa;
      acc = __builtin_amdgcn_mfma_f32_16x16x32_bf16(b00, a0, acc, 0, 0, 0);
      acc = __builtin_amdgcn_mfma_f32_16x16x32_bf16(b01, a1, acc, 0, 0, 0);
      #pragma unroll
      for (int r = 0; r < 4; ++r)
        p = fmaf(wsa[r], __builtin_amdgcn_rcpf(__builtin_amdgcn_exp2f(acc[r]) + 1.f), p);
      f32x4 acc2 = qb;
      acc2 = __builtin_amdgcn_mfma_f32_16x16x32_bf16(b10, a0, acc2, 0, 0, 0);
      acc2 = __builtin_amdgcn_mfma_f32_16x16x32_bf16(b11, a1, acc2, 0, 0, 0);
      #pragma unroll
      for (int r = 0; r < 4; ++r)
        p = fmaf(wsb[r], __builtin_amdgcn_rcpf(__builtin_amdgcn_exp2f(acc2[r]) + 1.f), p);
      p += __shfl_xor(p, 16);    // sum over o across g-groups
      p += __shfl_xor(p, 32);
      if (g == 0) {
        int idx = half * 64 + mt * 16 + l15;
        scs[head_l][idx] = h ? (scs[head_l][idx] + p) : p;
      }
    }
  }

  __syncthreads();   // barrier 2: both halves' scores visible

  // ---- Phase D: softmax over n=127 (redundant per half; keep own half's weights) ----
  float w0, w1, w2, w3;
  {
    float s0 = scs[head_l][l15 + 0],  s1 = scs[head_l][l15 + 16];
    float s2 = scs[head_l][l15 + 32], s3 = scs[head_l][l15 + 48];
    float s4 = scs[head_l][l15 + 64], s5 = scs[head_l][l15 + 80];
    float s6 = scs[head_l][l15 + 96], s7 = scs[head_l][l15 + 112];
    if (l15 == 15) s7 = -3.0e38f;   // mask pad row n=127
    float m = fmaxf(fmaxf(fmaxf(s0, s1), fmaxf(s2, s3)),
                    fmaxf(fmaxf(s4, s5), fmaxf(s6, s7)));
    #pragma unroll
    for (int d = 1; d < 16; d <<= 1) m = fmaxf(m, __shfl_xor(m, d));
    float e0 = __expf(s0 - m), e1 = __expf(s1 - m), e2 = __expf(s2 - m), e3 = __expf(s3 - m);
    float e4 = __expf(s4 - m), e5 = __expf(s5 - m), e6 = __expf(s6 - m), e7 = __expf(s7 - m);
    float sum = ((e0 + e1) + (e2 + e3)) + ((e4 + e5) + (e6 + e7));
    #pragma unroll
    for (int d = 1; d < 16; d <<= 1) sum += __shfl_xor(sum, d);
    float inv = __builtin_amdgcn_rcpf(sum);
    if (half) { w0 = e4 * inv; w1 = e5 * inv; w2 = e6 * inv; w3 = e7 * inv; }
    else      { w0 = e0 * inv; w1 = e1 * inv; w2 = e2 * inv; w3 = e3 * inv; }
  }

  // ---- Phase E: pvp[k] = sum over this wave's 64 rows of P[n]*kv[n,k] ----
  float pvp0[8], pvp1[8];
  #pragma unroll
  for (int j = 0; j < 8; ++j) { pvp0[j] = 0.f; pvp1[j] = 0.f; }
  #pragma unroll 1
  for (int mt = 0; mt < 4; ++mt) {
    int row = half * 64 + mt * 16 + l15;
    int byte0 = (row << 7) + g * 16;
    int swz = (l15 & 7) << 4;
    bf16x8 a0 = *(const bf16x8*)(&Atile[byte0 ^ swz]);
    bf16x8 a1 = *(const bf16x8*)(&Atile[(byte0 + 64) ^ swz]);
    float w = (mt == 0) ? w0 : (mt == 1) ? w1 : (mt == 2) ? w2 : w3;  // static names
    #pragma unroll
    for (int j = 0; j < 8; ++j) {
      pvp0[j] = fmaf(w, b2f(a0[j]), pvp0[j]);
      pvp1[j] = fmaf(w, b2f(a1[j]), pvp1[j]);
    }
  }
  bf16x8 pa0, pa1;
  #pragma unroll
  for (int j = 0; j < 8; ++j) { pa0[j] = bfs(pvp0[j]); pa1[j] = bfs(pvp1[j]); }

  // ---- GEMV: partial out[o] for this half; MFMA i-dim folds the 16 row-groups ----
  #pragma unroll 1
  for (int nt = 0; nt < 4; ++nt) {
    bf16x8 bw0, bw1;
    if (PREP) {
      const bf16x8* pw = (const bf16x8*)(pack + WVP_S);
      bw0 = pw[((head * 4 + nt) * 2 + 0) * 64 + lane];
      bw1 = pw[((head * 4 + nt) * 2 + 1) * 64 + lane];
    } else {
      int o = head * 64 + nt * 16 + l15;
      bw0 = gath_s(Wv + o * 128 + g * 8, 1.f);
      bw1 = gath_s(Wv + o * 128 + 32 + g * 8, 1.f);
    }
    f32x4 c = (f32x4){0.f, 0.f, 0.f, 0.f};
    c = __builtin_amdgcn_mfma_f32_16x16x32_bf16(pa0, bw0, c, 0, 0, 0);
    c = __builtin_amdgcn_mfma_f32_16x16x32_bf16(pa1, bw1, c, 0, 0, 0);
    float t = (c[0] + c[1]) + (c[2] + c[3]);
    t += __shfl_xor(t, 16);
    t += __shfl_xor(t, 32);
    if (g == 0) ps[wv][nt * 16 + l15] = t;
  }

  __syncthreads();   // barrier 3: both halves' partials visible

  // ---- combine halves + qv, store (half==0 waves; fully coalesced 64-lane store) ----
  if (half == 0) {
    float v = ps[wv][lane] + ps[wv + 1][lane];
    float qv = ((const float*)&qv_lds[head_l][lane >> 4][(lane & 15) >> 2])[lane & 3];
    out[bt * 256 + head * 64 + lane] = v + qv;
  }
}

extern "C" void kernel_launch(void* const* d_in, const int* in_sizes, int n_in,
                              void* d_out, int out_size, void* d_ws, size_t ws_size,
                              hipStream_t stream) {
  const float* q_x  = (const float*)d_in[0];
  const float* kv_x = (const float*)d_in[1];
  const float* Wk   = (const float*)d_in[2];
  const float* Wq   = (const float*)d_in[3];
  const float* Wv   = (const float*)d_in[4];
  const float* bv   = (const float*)d_in[5];
  const float* bias = (const float*)d_in[6];
  const float* wsc  = (const float*)d_in[7];
  // d_in[8] = bs: constant across neighbors -> cancels in softmax, unused.
  float* out = (float*)d_out;
  short* pack = (short*)d_ws;

  if (ws_size >= WS_NEEDED) {
    pack_kernel<<<64, 256, 0, stream>>>(Wk, Wq, Wv, pack);
    rnn_attn_kernel<1><<<2048, 256, 0, stream>>>(q_x, kv_x, Wk, Wq, Wv, bv, bias, wsc, pack, out);
  } else {
    rnn_attn_kernel<0><<<2048, 256, 0, stream>>>(q_x, kv_x, Wk, Wq, Wv, bv, bias, wsc, pack, out);
  }
}

// Round 15
// 29.581 us; speedup vs baseline: 1.7969x; 1.1597x over previous
//
#include <hip/hip_runtime.h>
#include <hip/hip_bf16.h>

// Problem constants: B=8, T=128, n=127 neighbors, Q=K=64, H=4, O=H*K=256
#define NB 127
#define SCALE 2.885390081777927f   // 2*log2(e): folds tanh's e^{2x} into one exp2

typedef __attribute__((ext_vector_type(8))) short bf16x8;
typedef __attribute__((ext_vector_type(4))) float f32x4;

// ws layout: packed bf16 MFMA fragments, 4 x 32KB (short offsets).
// Wk and Wq are PRE-SCALED by SCALE in the pack kernel.
#define WKP_S  0
#define WVP_S  16384
#define WQP_S  32768
#define WVQP_S 49152
#define WS_NEEDED ((size_t)(4 * 16384 * 2))

__device__ __forceinline__ short bfs(float f) {
  __hip_bfloat16 h = __float2bfloat16(f);
  return __builtin_bit_cast(short, h);
}
__device__ __forceinline__ unsigned packbf2(float a, float b) {
  unsigned lo = (unsigned short)bfs(a);
  unsigned hi = (unsigned short)bfs(b);
  return lo | (hi << 16);
}
__device__ __forceinline__ float b2f(short s) {
  unsigned u = ((unsigned)(unsigned short)s) << 16;
  return __builtin_bit_cast(float, u);
}
__device__ __forceinline__ bf16x8 gath_s(const float* __restrict__ p, float s) {
  float4 a = *(const float4*)p;
  float4 b = *(const float4*)(p + 4);
  bf16x8 f;
  f[0] = bfs(a.x * s); f[1] = bfs(a.y * s); f[2] = bfs(a.z * s); f[3] = bfs(a.w * s);
  f[4] = bfs(b.x * s); f[5] = bfs(b.y * s); f[6] = bfs(b.z * s); f[7] = bfs(b.w * s);
  return f;
}
// sigmoid-like term: 1/(exp2(x)+1)
__device__ __forceinline__ float sigt(float x) {
  return __builtin_amdgcn_rcpf(__builtin_amdgcn_exp2f(x) + 1.f);
}

// ================= pack kernel (grid 64): coalesced f32 reads -> fragment-order bf16 ====
// frag layout: lane (= g*16 + l15) of fragment (head,nt,kt) holds
//   W[o = head*64 + nt*16 + l15][k = g*8 + kt*32 + j], j=0..7
__global__ __launch_bounds__(256, 2) void
pack_kernel(const float* __restrict__ Wk, const float* __restrict__ Wq,
            const float* __restrict__ Wv, short* __restrict__ dstall)
{
  const int blk = blockIdx.x;
  const int tid = threadIdx.x;
  const int m = blk >> 4, sub = blk & 15;
  const float* src; int stride, off, dsto; float scl;
  if (m == 0)      { src = Wk; stride = 64;  off = 0;  dsto = WKP_S;  scl = SCALE; }
  else if (m == 1) { src = Wv; stride = 128; off = 0;  dsto = WVP_S;  scl = 1.f; }  // Wv kv
  else if (m == 2) { src = Wq; stride = 64;  off = 0;  dsto = WQP_S;  scl = SCALE; }
  else             { src = Wv; stride = 128; off = 64; dsto = WVQP_S; scl = 1.f; }  // Wv q
  short* dst = dstall + dsto;
  int i4 = sub * 256 + tid;               // float4 index in 256x64 submatrix
  int o = i4 >> 4, c4 = i4 & 15;
  float4 v = ((const float4*)(src + o * stride + off))[c4];
  int k0 = c4 * 4;
  int kt = k0 >> 5, gg = (k0 & 31) >> 3, j0 = k0 & 7;
  int head = o >> 6, nt = (o >> 4) & 3, ol = o & 15;
  int di = ((((head * 4 + nt) * 2 + kt) * 64) + gg * 16 + ol) * 8 + j0;
  *(uint2*)(dst + di) = make_uint2(packbf2(v.x * scl, v.y * scl),
                                   packbf2(v.z * scl, v.w * scl));
}

// ================= main kernel (grid 1024, wave = head) =================
// R10 structure (proven 29.1us, spill-free) + ONE change: Phase C's score
// accumulation uses 4 independent partials (serial fmaf depth 8 -> 2), letting
// the 8 exp2/rcp pairs pipeline instead of chaining.
template <int PREP>
__global__ __launch_bounds__(256, 4) void
rnn_attn_kernel(const float* __restrict__ q_x, const float* __restrict__ kv_x,
                const float* __restrict__ Wk, const float* __restrict__ Wq,
                const float* __restrict__ Wv, const float* __restrict__ bv,
                const float* __restrict__ bias, const float* __restrict__ wsc,
                const short* __restrict__ pack, float* __restrict__ out)
{
  __shared__ __align__(16) unsigned char Atile[128 * 128];
  __shared__ float scs[4][128];        // per-head scores -> softmax weights
  __shared__ float4 qv_lds[4][4][4];   // [head][nt][g] : qv[o = nt*16+g*4+r]

  const int tid = threadIdx.x;
  const int bt = blockIdx.x;
  const int lane = tid & 63;
  const int head = tid >> 6;
  const int l15 = lane & 15;
  const int g = lane >> 4;

  // ---- stage kv tile (127x64 f32 -> bf16, XOR-swizzled), coalesced ----
  const float* kv = kv_x + (size_t)bt * (NB * 64);
  #pragma unroll
  for (int i = 0; i < 8; ++i) {
    int idx = i * 256 + tid;
    int row = idx >> 4, c = idx & 15;
    float4 v = (row < NB) ? ((const float4*)kv)[idx] : make_float4(0.f, 0.f, 0.f, 0.f);
    int byte = (row << 7) + (c << 3);
    byte ^= ((row & 7) << 4);
    *(uint2*)(&Atile[byte]) = make_uint2(packbf2(v.x, v.y), packbf2(v.z, v.w));
  }

  // ---- prologue: qq/qv via broadcast-B MFMA (identical to R10) ----
  f32x4 qq[4];
  {
    bf16x8 qf0 = gath_s(q_x + bt * 64 + g * 8, 1.f);
    bf16x8 qf1 = gath_s(q_x + bt * 64 + 32 + g * 8, 1.f);
    #pragma unroll
    for (int nt = 0; nt < 4; ++nt) {
      bf16x8 wv0, wv1;
      if (PREP) {
        const bf16x8* pv = (const bf16x8*)(pack + WVQP_S);
        wv0 = pv[((head * 4 + nt) * 2 + 0) * 64 + lane];
        wv1 = pv[((head * 4 + nt) * 2 + 1) * 64 + lane];
      } else {
        int o = head * 64 + nt * 16 + l15;
        wv0 = gath_s(Wv + o * 128 + 64 + g * 8, 1.f);
        wv1 = gath_s(Wv + o * 128 + 64 + 32 + g * 8, 1.f);
      }
      float4 bv4 = ((const float4*)(bv + head * 64))[nt * 4 + g];
      f32x4 b = (f32x4){bv4.x, bv4.y, bv4.z, bv4.w};
      b = __builtin_amdgcn_mfma_f32_16x16x32_bf16(wv0, qf0, b, 0, 0, 0);
      b = __builtin_amdgcn_mfma_f32_16x16x32_bf16(wv1, qf1, b, 0, 0, 0);
      if (l15 == 0) qv_lds[head][nt][g] = make_float4(b[0], b[1], b[2], b[3]);
    }
    #pragma unroll
    for (int nt = 0; nt < 4; ++nt) {
      bf16x8 wq0, wq1;
      if (PREP) {
        const bf16x8* pw = (const bf16x8*)(pack + WQP_S);
        wq0 = pw[((head * 4 + nt) * 2 + 0) * 64 + lane];
        wq1 = pw[((head * 4 + nt) * 2 + 1) * 64 + lane];
      } else {
        int o = head * 64 + nt * 16 + l15;
        wq0 = gath_s(Wq + o * 64 + g * 8, SCALE);
        wq1 = gath_s(Wq + o * 64 + 32 + g * 8, SCALE);
      }
      float4 bs4 = ((const float4*)bias)[nt * 4 + g];
      f32x4 a = (f32x4){bs4.x * SCALE, bs4.y * SCALE, bs4.z * SCALE, bs4.w * SCALE};
      a = __builtin_amdgcn_mfma_f32_16x16x32_bf16(wq0, qf0, a, 0, 0, 0);
      a = __builtin_amdgcn_mfma_f32_16x16x32_bf16(wq1, qf1, a, 0, 0, 0);
      qq[nt] = a;
    }
  }

  __syncthreads();

  // ---- Phase C: keys^T GEMM + score, two o-halves; 4 independent partials ----
  #pragma unroll
  for (int h = 0; h < 2; ++h) {
    bf16x8 b00, b01, b10, b11;
    if (PREP) {
      const bf16x8* pw = (const bf16x8*)(pack + WKP_S);
      b00 = pw[((head * 4 + 2 * h + 0) * 2 + 0) * 64 + lane];
      b01 = pw[((head * 4 + 2 * h + 0) * 2 + 1) * 64 + lane];
      b10 = pw[((head * 4 + 2 * h + 1) * 2 + 0) * 64 + lane];
      b11 = pw[((head * 4 + 2 * h + 1) * 2 + 1) * 64 + lane];
    } else {
      int o0 = head * 64 + (2 * h) * 16 + l15;
      b00 = gath_s(Wk + o0 * 64 + g * 8, SCALE);
      b01 = gath_s(Wk + o0 * 64 + 32 + g * 8, SCALE);
      b10 = gath_s(Wk + (o0 + 16) * 64 + g * 8, SCALE);
      b11 = gath_s(Wk + (o0 + 16) * 64 + 32 + g * 8, SCALE);
    }
    float4 ta = ((const float4*)wsc)[(2 * h) * 4 + g];
    float4 tb = ((const float4*)wsc)[(2 * h + 1) * 4 + g];
    f32x4 wsa = (f32x4){-2.f * ta.x, -2.f * ta.y, -2.f * ta.z, -2.f * ta.w};
    f32x4 wsb = (f32x4){-2.f * tb.x, -2.f * tb.y, -2.f * tb.z, -2.f * tb.w};
    f32x4 qa = qq[2 * h], qb = qq[2 * h + 1];

    #pragma unroll 1
    for (int mt = 0; mt < 8; ++mt) {
      int row = mt * 16 + l15;
      int byte0 = (row << 7) + g * 16;
      int swz = (l15 & 7) << 4;
      bf16x8 a0 = *(const bf16x8*)(&Atile[byte0 ^ swz]);
      bf16x8 a1 = *(const bf16x8*)(&Atile[(byte0 + 64) ^ swz]);
      f32x4 acc = qa;
      acc = __builtin_amdgcn_mfma_f32_16x16x32_bf16(b00, a0, acc, 0, 0, 0);
      acc = __builtin_amdgcn_mfma_f32_16x16x32_bf16(b01, a1, acc, 0, 0, 0);
      f32x4 acc2 = qb;
      acc2 = __builtin_amdgcn_mfma_f32_16x16x32_bf16(b10, a0, acc2, 0, 0, 0);
      acc2 = __builtin_amdgcn_mfma_f32_16x16x32_bf16(b11, a1, acc2, 0, 0, 0);
      // 8 independent sigmoids; 4 independent accumulation chains (depth 2)
      float p0 = wsa[0] * sigt(acc[0]);
      float p1 = wsa[1] * sigt(acc[1]);
      float p2 = wsa[2] * sigt(acc[2]);
      float p3 = wsa[3] * sigt(acc[3]);
      p0 = fmaf(wsb[0], sigt(acc2[0]), p0);
      p1 = fmaf(wsb[1], sigt(acc2[1]), p1);
      p2 = fmaf(wsb[2], sigt(acc2[2]), p2);
      p3 = fmaf(wsb[3], sigt(acc2[3]), p3);
      float p = (p0 + p1) + (p2 + p3);
      p += __shfl_xor(p, 16);    // sum over o across g-groups
      p += __shfl_xor(p, 32);
      if (g == 0) {
        int idx = mt * 16 + l15;
        scs[head][idx] = h ? (scs[head][idx] + p) : p;
      }
    }
  }

  // ---- Phase D: softmax over n=127 (identical to R10) ----
  {
    float s0 = scs[head][l15 + 0],  s1 = scs[head][l15 + 16];
    float s2 = scs[head][l15 + 32], s3 = scs[head][l15 + 48];
    float s4 = scs[head][l15 + 64], s5 = scs[head][l15 + 80];
    float s6 = scs[head][l15 + 96], s7 = scs[head][l15 + 112];
    if (l15 == 15) s7 = -3.0e38f;   // mask pad row n=127
    float m = fmaxf(fmaxf(fmaxf(s0, s1), fmaxf(s2, s3)),
                    fmaxf(fmaxf(s4, s5), fmaxf(s6, s7)));
    #pragma unroll
    for (int d = 1; d < 16; d <<= 1) m = fmaxf(m, __shfl_xor(m, d));
    float e0 = __expf(s0 - m), e1 = __expf(s1 - m), e2 = __expf(s2 - m), e3 = __expf(s3 - m);
    float e4 = __expf(s4 - m), e5 = __expf(s5 - m), e6 = __expf(s6 - m), e7 = __expf(s7 - m);
    float sum = ((e0 + e1) + (e2 + e3)) + ((e4 + e5) + (e6 + e7));
    #pragma unroll
    for (int d = 1; d < 16; d <<= 1) sum += __shfl_xor(sum, d);
    float inv = __builtin_amdgcn_rcpf(sum);
    if (g == 0) {
      scs[head][l15 + 0]  = e0 * inv; scs[head][l15 + 16] = e1 * inv;
      scs[head][l15 + 32] = e2 * inv; scs[head][l15 + 48] = e3 * inv;
      scs[head][l15 + 64] = e4 * inv; scs[head][l15 + 80] = e5 * inv;
      scs[head][l15 + 96] = e6 * inv; scs[head][l15 + 112] = e7 * inv;
    }
  }

  // ---- Phase E: pvp[k] = sum_n P[n]*kv[n,k], single VALU tile sweep ----
  float pvp0[8], pvp1[8];
  #pragma unroll
  for (int j = 0; j < 8; ++j) { pvp0[j] = 0.f; pvp1[j] = 0.f; }
  #pragma unroll 1
  for (int mt = 0; mt < 8; ++mt) {
    int row = mt * 16 + l15;
    int byte0 = (row << 7) + g * 16;
    int swz = (l15 & 7) << 4;
    bf16x8 a0 = *(const bf16x8*)(&Atile[byte0 ^ swz]);
    bf16x8 a1 = *(const bf16x8*)(&Atile[(byte0 + 64) ^ swz]);
    float w = scs[head][mt * 16 + l15];   // broadcast across g-groups
    #pragma unroll
    for (int j = 0; j < 8; ++j) {
      pvp0[j] = fmaf(w, b2f(a0[j]), pvp0[j]);
      pvp1[j] = fmaf(w, b2f(a1[j]), pvp1[j]);
    }
  }
  // pvp is an A-fragment: lane (l15,g) = pv_partial[group=l15][k = g*8+j (+32)]
  bf16x8 pa0, pa1;
  #pragma unroll
  for (int j = 0; j < 8; ++j) { pa0[j] = bfs(pvp0[j]); pa1[j] = bfs(pvp1[j]); }

  // ---- GEMV: out[o] = sum_k pv[k]*Wv_kv[o,k]; MFMA i-dim folds the 16 partials ----
  float tt[4];
  #pragma unroll 2
  for (int nt = 0; nt < 4; ++nt) {
    bf16x8 bw0, bw1;
    if (PREP) {
      const bf16x8* pw = (const bf16x8*)(pack + WVP_S);
      bw0 = pw[((head * 4 + nt) * 2 + 0) * 64 + lane];
      bw1 = pw[((head * 4 + nt) * 2 + 1) * 64 + lane];
    } else {
      int o = head * 64 + nt * 16 + l15;
      bw0 = gath_s(Wv + o * 128 + g * 8, 1.f);
      bw1 = gath_s(Wv + o * 128 + 32 + g * 8, 1.f);
    }
    f32x4 c = (f32x4){0.f, 0.f, 0.f, 0.f};
    c = __builtin_amdgcn_mfma_f32_16x16x32_bf16(pa0, bw0, c, 0, 0, 0);
    c = __builtin_amdgcn_mfma_f32_16x16x32_bf16(pa1, bw1, c, 0, 0, 0);
    float t = (c[0] + c[1]) + (c[2] + c[3]);
    t += __shfl_xor(t, 16);
    t += __shfl_xor(t, 32);
    tt[nt] = t;            // out-partial for o = nt*16 + l15, valid in all lanes
  }

  // ---- store: lane (l15,g) writes o = g*16 + l15 -> fully coalesced ----
  float v = tt[0];
  v = (g == 1) ? tt[1] : v;
  v = (g == 2) ? tt[2] : v;
  v = (g == 3) ? tt[3] : v;
  float qv = ((const float*)&qv_lds[head][g][l15 >> 2])[l15 & 3];
  out[bt * 256 + head * 64 + lane] = v + qv;
}

extern "C" void kernel_launch(void* const* d_in, const int* in_sizes, int n_in,
                              void* d_out, int out_size, void* d_ws, size_t ws_size,
                              hipStream_t stream) {
  const float* q_x  = (const float*)d_in[0];
  const float* kv_x = (const float*)d_in[1];
  const float* Wk   = (const float*)d_in[2];
  const float* Wq   = (const float*)d_in[3];
  const float* Wv   = (const float*)d_in[4];
  const float* bv   = (const float*)d_in[5];
  const float* bias = (const float*)d_in[6];
  const float* wsc  = (const float*)d_in[7];
  // d_in[8] = bs: constant across neighbors -> cancels in softmax, unused.
  float* out = (float*)d_out;
  short* pack = (short*)d_ws;

  if (ws_size >= WS_NEEDED) {
    pack_kernel<<<64, 256, 0, stream>>>(Wk, Wq, Wv, pack);
    rnn_attn_kernel<1><<<1024, 256, 0, stream>>>(q_x, kv_x, Wk, Wq, Wv, bv, bias, wsc, pack, out);
  } else {
    rnn_attn_kernel<0><<<1024, 256, 0, stream>>>(q_x, kv_x, Wk, Wq, Wv, bv, bias, wsc, pack, out);
  }
}

// Round 17
// 28.004 us; speedup vs baseline: 1.8981x; 1.0563x over previous
//
#include <hip/hip_runtime.h>
#include <hip/hip_bf16.h>

// Problem constants: B=8, T=128, n=127 neighbors, Q=K=64, H=4, O=H*K=256
#define NB 127
#define SCALE 2.885390081777927f   // 2*log2(e): folds tanh's e^{2x} into one exp2

typedef __attribute__((ext_vector_type(8))) short bf16x8;
typedef __attribute__((ext_vector_type(4))) float f32x4;

// ws layout: packed bf16 MFMA fragments, 4 x 32KB (short offsets).
// Wk and Wq are PRE-SCALED by SCALE in the pack kernel.
#define WKP_S  0
#define WVP_S  16384
#define WQP_S  32768
#define WVQP_S 49152
#define WS_NEEDED ((size_t)(4 * 16384 * 2))

__device__ __forceinline__ short bfs(float f) {
  __hip_bfloat16 h = __float2bfloat16(f);
  return __builtin_bit_cast(short, h);
}
__device__ __forceinline__ unsigned packbf2(float a, float b) {
  unsigned lo = (unsigned short)bfs(a);
  unsigned hi = (unsigned short)bfs(b);
  return lo | (hi << 16);
}
__device__ __forceinline__ float b2f(short s) {
  unsigned u = ((unsigned)(unsigned short)s) << 16;
  return __builtin_bit_cast(float, u);
}
__device__ __forceinline__ bf16x8 gath_s(const float* __restrict__ p, float s) {
  float4 a = *(const float4*)p;
  float4 b = *(const float4*)(p + 4);
  bf16x8 f;
  f[0] = bfs(a.x * s); f[1] = bfs(a.y * s); f[2] = bfs(a.z * s); f[3] = bfs(a.w * s);
  f[4] = bfs(b.x * s); f[5] = bfs(b.y * s); f[6] = bfs(b.z * s); f[7] = bfs(b.w * s);
  return f;
}
// sigmoid-like term: 1/(exp2(x)+1)
__device__ __forceinline__ float sigt(float x) {
  return __builtin_amdgcn_rcpf(__builtin_amdgcn_exp2f(x) + 1.f);
}

// ================= pack kernel (grid 64): coalesced f32 reads -> fragment-order bf16 ====
// frag layout: lane (= g*16 + l15) of fragment (head,nt,kt) holds
//   W[o = head*64 + nt*16 + l15][k = g*8 + kt*32 + j], j=0..7
__global__ __launch_bounds__(256, 2) void
pack_kernel(const float* __restrict__ Wk, const float* __restrict__ Wq,
            const float* __restrict__ Wv, short* __restrict__ dstall)
{
  const int blk = blockIdx.x;
  const int tid = threadIdx.x;
  const int m = blk >> 4, sub = blk & 15;
  const float* src; int stride, off, dsto; float scl;
  if (m == 0)      { src = Wk; stride = 64;  off = 0;  dsto = WKP_S;  scl = SCALE; }
  else if (m == 1) { src = Wv; stride = 128; off = 0;  dsto = WVP_S;  scl = 1.f; }  // Wv kv
  else if (m == 2) { src = Wq; stride = 64;  off = 0;  dsto = WQP_S;  scl = SCALE; }
  else             { src = Wv; stride = 128; off = 64; dsto = WVQP_S; scl = 1.f; }  // Wv q
  short* dst = dstall + dsto;
  int i4 = sub * 256 + tid;               // float4 index in 256x64 submatrix
  int o = i4 >> 4, c4 = i4 & 15;
  float4 v = ((const float4*)(src + o * stride + off))[c4];
  int k0 = c4 * 4;
  int kt = k0 >> 5, gg = (k0 & 31) >> 3, j0 = k0 & 7;
  int head = o >> 6, nt = (o >> 4) & 3, ol = o & 15;
  int di = ((((head * 4 + nt) * 2 + kt) * 64) + gg * 16 + ol) * 8 + j0;
  *(uint2*)(dst + di) = make_uint2(packbf2(v.x * scl, v.y * scl),
                                   packbf2(v.z * scl, v.w * scl));
}

// ================= main kernel (grid 1024, wave = head) =================
// FUSED single tile sweep (R16) + FIX: z (softmax denominator) must be reduced
// across l15 lanes (shfl_xor 1/2/4/8) before rcp — pvp stays l15-partial (the
// GEMV's MFMA i-dim folds it), but z is a full-row-space sum. R16 forgot this
// and produced ~16x inflated outputs.
template <int PREP>
__global__ __launch_bounds__(256, 2) void
rnn_attn_kernel(const float* __restrict__ q_x, const float* __restrict__ kv_x,
                const float* __restrict__ Wk, const float* __restrict__ Wq,
                const float* __restrict__ Wv, const float* __restrict__ bv,
                const float* __restrict__ bias, const float* __restrict__ wsc,
                const short* __restrict__ pack, float* __restrict__ out)
{
  __shared__ __align__(16) unsigned char Atile[128 * 128];
  __shared__ float4 qv_lds[4][4][4];   // [head][nt][g] : qv[o = nt*16+g*4+r]

  const int tid = threadIdx.x;
  const int bt = blockIdx.x;
  const int lane = tid & 63;
  const int head = tid >> 6;
  const int l15 = lane & 15;
  const int g = lane >> 4;

  // ---- stage kv tile (127x64 f32 -> bf16, XOR-swizzled), coalesced ----
  const float* kv = kv_x + (size_t)bt * (NB * 64);
  #pragma unroll
  for (int i = 0; i < 8; ++i) {
    int idx = i * 256 + tid;
    int row = idx >> 4, c = idx & 15;
    float4 v = (row < NB) ? ((const float4*)kv)[idx] : make_float4(0.f, 0.f, 0.f, 0.f);
    int byte = (row << 7) + (c << 3);
    byte ^= ((row & 7) << 4);
    *(uint2*)(&Atile[byte]) = make_uint2(packbf2(v.x, v.y), packbf2(v.z, v.w));
  }

  // ---- prologue: qq/qv via broadcast-B MFMA (identical to R10) ----
  f32x4 qq[4];
  {
    bf16x8 qf0 = gath_s(q_x + bt * 64 + g * 8, 1.f);
    bf16x8 qf1 = gath_s(q_x + bt * 64 + 32 + g * 8, 1.f);
    #pragma unroll
    for (int nt = 0; nt < 4; ++nt) {
      bf16x8 wv0, wv1;
      if (PREP) {
        const bf16x8* pv = (const bf16x8*)(pack + WVQP_S);
        wv0 = pv[((head * 4 + nt) * 2 + 0) * 64 + lane];
        wv1 = pv[((head * 4 + nt) * 2 + 1) * 64 + lane];
      } else {
        int o = head * 64 + nt * 16 + l15;
        wv0 = gath_s(Wv + o * 128 + 64 + g * 8, 1.f);
        wv1 = gath_s(Wv + o * 128 + 64 + 32 + g * 8, 1.f);
      }
      float4 bv4 = ((const float4*)(bv + head * 64))[nt * 4 + g];
      f32x4 b = (f32x4){bv4.x, bv4.y, bv4.z, bv4.w};
      b = __builtin_amdgcn_mfma_f32_16x16x32_bf16(wv0, qf0, b, 0, 0, 0);
      b = __builtin_amdgcn_mfma_f32_16x16x32_bf16(wv1, qf1, b, 0, 0, 0);
      if (l15 == 0) qv_lds[head][nt][g] = make_float4(b[0], b[1], b[2], b[3]);
    }
    #pragma unroll
    for (int nt = 0; nt < 4; ++nt) {
      bf16x8 wq0, wq1;
      if (PREP) {
        const bf16x8* pw = (const bf16x8*)(pack + WQP_S);
        wq0 = pw[((head * 4 + nt) * 2 + 0) * 64 + lane];
        wq1 = pw[((head * 4 + nt) * 2 + 1) * 64 + lane];
      } else {
        int o = head * 64 + nt * 16 + l15;
        wq0 = gath_s(Wq + o * 64 + g * 8, SCALE);
        wq1 = gath_s(Wq + o * 64 + 32 + g * 8, SCALE);
      }
      float4 bs4 = ((const float4*)bias)[nt * 4 + g];
      f32x4 a = (f32x4){bs4.x * SCALE, bs4.y * SCALE, bs4.z * SCALE, bs4.w * SCALE};
      a = __builtin_amdgcn_mfma_f32_16x16x32_bf16(wq0, qf0, a, 0, 0, 0);
      a = __builtin_amdgcn_mfma_f32_16x16x32_bf16(wq1, qf1, a, 0, 0, 0);
      qq[nt] = a;
    }
  }

  // ---- score weights + ALL FOUR Wk fragment pairs (single-pass C) ----
  f32x4 ws4[4];
  bf16x8 bk[4][2];
  #pragma unroll
  for (int nt = 0; nt < 4; ++nt) {
    float4 t = ((const float4*)wsc)[nt * 4 + g];
    ws4[nt] = (f32x4){-2.f * t.x, -2.f * t.y, -2.f * t.z, -2.f * t.w};
    if (PREP) {
      const bf16x8* pw = (const bf16x8*)(pack + WKP_S);
      bk[nt][0] = pw[((head * 4 + nt) * 2 + 0) * 64 + lane];
      bk[nt][1] = pw[((head * 4 + nt) * 2 + 1) * 64 + lane];
    } else {
      int o = head * 64 + nt * 16 + l15;
      bk[nt][0] = gath_s(Wk + o * 64 + g * 8, SCALE);
      bk[nt][1] = gath_s(Wk + o * 64 + 32 + g * 8, SCALE);
    }
  }

  __syncthreads();   // the only barrier

  // ---- FUSED sweep: score -> unnormalized softmax -> pv accumulate ----
  float pvp0[8], pvp1[8], z = 0.f;
  #pragma unroll
  for (int j = 0; j < 8; ++j) { pvp0[j] = 0.f; pvp1[j] = 0.f; }
  #pragma unroll 1
  for (int mt = 0; mt < 8; ++mt) {
    int row = mt * 16 + l15;
    int byte0 = (row << 7) + g * 16;
    int swz = (l15 & 7) << 4;
    bf16x8 a0 = *(const bf16x8*)(&Atile[byte0 ^ swz]);
    bf16x8 a1 = *(const bf16x8*)(&Atile[(byte0 + 64) ^ swz]);
    // scores for 16 o-values of this lane (4 nt x 4 r), 4 independent partials
    float pp0, pp1, pp2, pp3;
    {
      f32x4 acc = qq[0];
      acc = __builtin_amdgcn_mfma_f32_16x16x32_bf16(bk[0][0], a0, acc, 0, 0, 0);
      acc = __builtin_amdgcn_mfma_f32_16x16x32_bf16(bk[0][1], a1, acc, 0, 0, 0);
      pp0 = ws4[0][0] * sigt(acc[0]);
      pp0 = fmaf(ws4[0][1], sigt(acc[1]), pp0);
      pp0 = fmaf(ws4[0][2], sigt(acc[2]), pp0);
      pp0 = fmaf(ws4[0][3], sigt(acc[3]), pp0);
    }
    {
      f32x4 acc = qq[1];
      acc = __builtin_amdgcn_mfma_f32_16x16x32_bf16(bk[1][0], a0, acc, 0, 0, 0);
      acc = __builtin_amdgcn_mfma_f32_16x16x32_bf16(bk[1][1], a1, acc, 0, 0, 0);
      pp1 = ws4[1][0] * sigt(acc[0]);
      pp1 = fmaf(ws4[1][1], sigt(acc[1]), pp1);
      pp1 = fmaf(ws4[1][2], sigt(acc[2]), pp1);
      pp1 = fmaf(ws4[1][3], sigt(acc[3]), pp1);
    }
    {
      f32x4 acc = qq[2];
      acc = __builtin_amdgcn_mfma_f32_16x16x32_bf16(bk[2][0], a0, acc, 0, 0, 0);
      acc = __builtin_amdgcn_mfma_f32_16x16x32_bf16(bk[2][1], a1, acc, 0, 0, 0);
      pp2 = ws4[2][0] * sigt(acc[0]);
      pp2 = fmaf(ws4[2][1], sigt(acc[1]), pp2);
      pp2 = fmaf(ws4[2][2], sigt(acc[2]), pp2);
      pp2 = fmaf(ws4[2][3], sigt(acc[3]), pp2);
    }
    {
      f32x4 acc = qq[3];
      acc = __builtin_amdgcn_mfma_f32_16x16x32_bf16(bk[3][0], a0, acc, 0, 0, 0);
      acc = __builtin_amdgcn_mfma_f32_16x16x32_bf16(bk[3][1], a1, acc, 0, 0, 0);
      pp3 = ws4[3][0] * sigt(acc[0]);
      pp3 = fmaf(ws4[3][1], sigt(acc[1]), pp3);
      pp3 = fmaf(ws4[3][2], sigt(acc[2]), pp3);
      pp3 = fmaf(ws4[3][3], sigt(acc[3]), pp3);
    }
    float p = (pp0 + pp1) + (pp2 + pp3);
    p += __shfl_xor(p, 16);    // full score for row n = mt*16+l15, all lanes
    p += __shfl_xor(p, 32);
    // unnormalized softmax weight (|p| <= Sigma|ws| ~ 2.6 -> exp safe, no max)
    float e = __expf(p);
    if (mt == 7 && l15 == 15) e = 0.f;   // pad row n=127
    z += e;
    #pragma unroll
    for (int j = 0; j < 8; ++j) {
      pvp0[j] = fmaf(e, b2f(a0[j]), pvp0[j]);
      pvp1[j] = fmaf(e, b2f(a1[j]), pvp1[j]);
    }
  }

  // ---- THE FIX: z currently holds only this lane's 8 rows; reduce across l15 ----
  z += __shfl_xor(z, 1);
  z += __shfl_xor(z, 2);
  z += __shfl_xor(z, 4);
  z += __shfl_xor(z, 8);
  float rz = __builtin_amdgcn_rcpf(z);

  // ---- normalize and convert pvp to an A-fragment ----
  bf16x8 pa0, pa1;
  #pragma unroll
  for (int j = 0; j < 8; ++j) { pa0[j] = bfs(pvp0[j] * rz); pa1[j] = bfs(pvp1[j] * rz); }

  // ---- GEMV: out[o] = sum_k pv[k]*Wv_kv[o,k]; MFMA i-dim folds the 16 partials ----
  float tt[4];
  #pragma unroll 2
  for (int nt = 0; nt < 4; ++nt) {
    bf16x8 bw0, bw1;
    if (PREP) {
      const bf16x8* pw = (const bf16x8*)(pack + WVP_S);
      bw0 = pw[((head * 4 + nt) * 2 + 0) * 64 + lane];
      bw1 = pw[((head * 4 + nt) * 2 + 1) * 64 + lane];
    } else {
      int o = head * 64 + nt * 16 + l15;
      bw0 = gath_s(Wv + o * 128 + g * 8, 1.f);
      bw1 = gath_s(Wv + o * 128 + 32 + g * 8, 1.f);
    }
    f32x4 c = (f32x4){0.f, 0.f, 0.f, 0.f};
    c = __builtin_amdgcn_mfma_f32_16x16x32_bf16(pa0, bw0, c, 0, 0, 0);
    c = __builtin_amdgcn_mfma_f32_16x16x32_bf16(pa1, bw1, c, 0, 0, 0);
    float t = (c[0] + c[1]) + (c[2] + c[3]);
    t += __shfl_xor(t, 16);
    t += __shfl_xor(t, 32);
    tt[nt] = t;            // out-partial for o = nt*16 + l15, valid in all lanes
  }

  // ---- store: lane (l15,g) writes o = g*16 + l15 -> fully coalesced ----
  float v = tt[0];
  v = (g == 1) ? tt[1] : v;
  v = (g == 2) ? tt[2] : v;
  v = (g == 3) ? tt[3] : v;
  float qv = ((const float*)&qv_lds[head][g][l15 >> 2])[l15 & 3];
  out[bt * 256 + head * 64 + lane] = v + qv;
}

extern "C" void kernel_launch(void* const* d_in, const int* in_sizes, int n_in,
                              void* d_out, int out_size, void* d_ws, size_t ws_size,
                              hipStream_t stream) {
  const float* q_x  = (const float*)d_in[0];
  const float* kv_x = (const float*)d_in[1];
  const float* Wk   = (const float*)d_in[2];
  const float* Wq   = (const float*)d_in[3];
  const float* Wv   = (const float*)d_in[4];
  const float* bv   = (const float*)d_in[5];
  const float* bias = (const float*)d_in[6];
  const float* wsc  = (const float*)d_in[7];
  // d_in[8] = bs: constant across neighbors -> cancels in softmax, unused.
  float* out = (float*)d_out;
  short* pack = (short*)d_ws;

  if (ws_size >= WS_NEEDED) {
    pack_kernel<<<64, 256, 0, stream>>>(Wk, Wq, Wv, pack);
    rnn_attn_kernel<1><<<1024, 256, 0, stream>>>(q_x, kv_x, Wk, Wq, Wv, bv, bias, wsc, pack, out);
  } else {
    rnn_attn_kernel<0><<<1024, 256, 0, stream>>>(q_x, kv_x, Wk, Wq, Wv, bv, bias, wsc, pack, out);
  }
}